// Round 8
// baseline (928.666 us; speedup 1.0000x reference)
//
#include <hip/hip_runtime.h>
#include <hip/hip_fp16.h>
#include <math.h>

#define NN 50000
#define EE 800000
#define DD 512
#define HH 256
#define KK 16
#define NB_SCAN 196   // ceil(NN/256)
#define NPAD 50048    // NN rounded to 64-node groups
#define NBINS 512

typedef _Float16 half8_t __attribute__((ext_vector_type(8)));
typedef float f32x4 __attribute__((ext_vector_type(4)));

// ---------------- utility ----------------
__global__ void zero_kernel(int* __restrict__ p, int n) {
    int i = blockIdx.x * blockDim.x + threadIdx.x;
    if (i < n) p[i] = 0;
}

__global__ void count_kernel(const int4* __restrict__ src4, const int4* __restrict__ dst4,
                             int* __restrict__ indeg, int* __restrict__ outdeg) {
    int e = blockIdx.x * blockDim.x + threadIdx.x;
    if (e < EE / 4) {
        int4 s = src4[e], d = dst4[e];
        atomicAdd(&outdeg[s.x], 1); atomicAdd(&outdeg[s.y], 1);
        atomicAdd(&outdeg[s.z], 1); atomicAdd(&outdeg[s.w], 1);
        atomicAdd(&indeg[d.x], 1);  atomicAdd(&indeg[d.y], 1);
        atomicAdd(&indeg[d.z], 1);  atomicAdd(&indeg[d.w], 1);
    }
}

// ---------------- scan phase 1 (+node_prep +degree histogram fused) ----------------
__global__ void scan_p1(const int* __restrict__ in, int* __restrict__ part, int n,
                        const int* __restrict__ outdeg, float* __restrict__ dis,
                        float* __restrict__ degf, int* __restrict__ hist) {
    __shared__ int tile[256];
    int t = threadIdx.x;
    int i = blockIdx.x * 256 + t;
    int v = (i < n) ? in[i] : 0;
    tile[t] = v;
    if (i < n) {
        dis[i]  = 1.0f / sqrtf(1.0f + (float)v);
        degf[i] = (float)outdeg[i];
        atomicAdd(&hist[min(v, NBINS - 1)], 1);
    }
    __syncthreads();
    for (int o = 128; o > 0; o >>= 1) {
        if (t < o) tile[t] += tile[t + o];
        __syncthreads();
    }
    if (t == 0) part[blockIdx.x] = tile[0];
}

__global__ void scan_p2(int* __restrict__ part, int nb, int* __restrict__ off_end) {
    __shared__ int tile[256];
    int t = threadIdx.x;
    int v = (t < nb) ? part[t] : 0;
    tile[t] = v;
    __syncthreads();
    for (int o = 1; o < 256; o <<= 1) {
        int x = (t >= o) ? tile[t - o] : 0;
        __syncthreads();
        tile[t] += x;
        __syncthreads();
    }
    if (t < nb) part[t] = tile[t] - v;  // exclusive base per block
    if (t == 255) *off_end = tile[255];
}

__global__ void scan_p3(const int* __restrict__ in, const int* __restrict__ part,
                        int* __restrict__ out, int n) {
    __shared__ int tile[256];
    int t = threadIdx.x;
    int i = blockIdx.x * 256 + t;
    int v = (i < n) ? in[i] : 0;
    tile[t] = v;
    __syncthreads();
    for (int o = 1; o < 256; o <<= 1) {
        int x = (t >= o) ? tile[t - o] : 0;
        __syncthreads();
        tile[t] += x;
        __syncthreads();
    }
    if (i < n) out[i] = part[blockIdx.x] + tile[t] - v;
}

// exclusive scan of hist[512] in place (single block), + pad perm tail with -1
__global__ void hist_scan(int* __restrict__ hist, int* __restrict__ perm) {
    __shared__ int tile[256];
    __shared__ int carry_s;
    int t = threadIdx.x;
    if (t == 0) carry_s = 0;
    if (t < NPAD - NN) perm[NN + t] = -1;
    __syncthreads();
    for (int base = 0; base < NBINS; base += 256) {
        int v = hist[base + t];
        tile[t] = v;
        __syncthreads();
        for (int o = 1; o < 256; o <<= 1) {
            int x = (t >= o) ? tile[t - o] : 0;
            __syncthreads();
            tile[t] += x;
            __syncthreads();
        }
        hist[base + t] = carry_s + tile[t] - v;  // exclusive
        __syncthreads();
        if (t == 0) carry_s += tile[255];
        __syncthreads();
    }
}

// perm[hoff[bin] + pos] = n, bin = min(indeg[n],511) -> degree-sorted node order
__global__ void perm_scatter(const int* __restrict__ indeg, const int* __restrict__ hoff,
                             int* __restrict__ cursor, int* __restrict__ perm) {
    int n = blockIdx.x * 256 + threadIdx.x;
    if (n < NN) {
        int bin = min(indeg[n], NBINS - 1);
        int p = atomicAdd(&cursor[bin], 1);
        perm[hoff[bin] + p] = n;
    }
}

// scatter edges into dst-CSR; also precompute edge weight w = dis[src]*dis[dst] (f16)
__global__ void scatter_kernel(const int4* __restrict__ src4, const int4* __restrict__ dst4,
                               const int* __restrict__ off, int* __restrict__ cur,
                               const float* __restrict__ dis,
                               int* __restrict__ nbr, __half* __restrict__ wgt) {
    int e = blockIdx.x * blockDim.x + threadIdx.x;
    if (e < EE / 4) {
        int4 s = src4[e], d = dst4[e];
        int p, q;
        p = atomicAdd(&cur[d.x], 1); q = off[d.x] + p;
        nbr[q] = s.x; wgt[q] = __float2half(dis[s.x] * dis[d.x]);
        p = atomicAdd(&cur[d.y], 1); q = off[d.y] + p;
        nbr[q] = s.y; wgt[q] = __float2half(dis[s.y] * dis[d.y]);
        p = atomicAdd(&cur[d.z], 1); q = off[d.z] + p;
        nbr[q] = s.z; wgt[q] = __float2half(dis[s.z] * dis[d.z]);
        p = atomicAdd(&cur[d.w], 1); q = off[d.w] + p;
        nbr[q] = s.w; wgt[q] = __float2half(dis[s.w] * dis[d.w]);
    }
}

// ---------------- fused weight transpose + f16 convert (W1, W2, Wa) ----------------
__global__ void transpose_w(const float* __restrict__ W1, __half* __restrict__ Wt1,
                            const float* __restrict__ W2, __half* __restrict__ Wt2,
                            const float* __restrict__ Wa, __half* __restrict__ WaT) {
    int i = blockIdx.x * 256 + threadIdx.x;
    if (i < DD * HH) {
        int k = i / HH, n = i % HH;
        Wt1[(size_t)n * DD + k] = __float2half(W1[i]);
    } else if (i < DD * HH + HH * HH) {
        int j = i - DD * HH;
        int k = j / HH, n = j % HH;
        Wt2[(size_t)n * HH + k] = __float2half(W2[j]);
    } else if (i < DD * HH + HH * HH + HH * KK) {
        int j = i - DD * HH - HH * HH;
        int k = j / KK, n = j % KK;
        WaT[n * HH + k] = __float2half(Wa[j]);
    }
}

// ---------------- MFMA f16 GEMM: T_sliced = A[M,KDIM] @ Wt[256,KDIM]^T ----------------
// Output written SLICE-MAJOR: T[(c>>5)*NN*32 + row*32 + (c&31)] (8 slices of 32 ch)
template <typename TA, int KDIM>
__global__ __launch_bounds__(256) void mfma_gemm(const TA* __restrict__ A,
                                                 const __half* __restrict__ Bt,
                                                 __half* __restrict__ C, int M) {
    constexpr bool F32 = sizeof(TA) == 4;
    constexpr int SROW = F32 ? 36 : 40;  // LDS row stride: 2-way bank alias max
    constexpr int EPG  = F32 ? 4 : 8;    // elements per 16B granule
    constexpr int GPR  = 32 / EPG;       // granules per k-row of 32
    constexpr int RPP  = 256 / GPR;      // rows staged per pass
    constexpr int NP   = 128 / RPP;      // staging passes
    constexpr int KI   = KDIM / 32;

    __shared__ TA As[2][128 * SROW];

    int t = threadIdx.x;
    int wave = t >> 6, lane = t & 63, quad = lane >> 4, l16 = lane & 15;
    int row0 = blockIdx.x * 128, col0 = blockIdx.y * 128;
    int wm = (wave & 1) * 64, wn = (wave >> 1) * 64;
    int srow = t / GPR, sg = t % GPR;

    f32x4 acc[4][4] = {};
    uint4 sreg[NP];
    uint4 bcur[4];

    const __half* brow[4];
#pragma unroll
    for (int ni = 0; ni < 4; ni++)
        brow[ni] = Bt + (size_t)(col0 + wn + ni * 16 + l16) * KDIM + quad * 8;

    auto gloadA = [&](int k0) {
#pragma unroll
        for (int p = 0; p < NP; p++) {
            int gr = row0 + p * RPP + srow;
            if (gr < M)
                sreg[p] = *(const uint4*)(A + (size_t)gr * KDIM + k0 + sg * EPG);
            else
                sreg[p] = make_uint4(0, 0, 0, 0);
        }
    };
    auto sstore = [&](int buf) {
#pragma unroll
        for (int p = 0; p < NP; p++)
            *(uint4*)&As[buf][(p * RPP + srow) * SROW + sg * EPG] = sreg[p];
    };

    gloadA(0);
#pragma unroll
    for (int ni = 0; ni < 4; ni++) bcur[ni] = *(const uint4*)(brow[ni]);
    sstore(0);
    __syncthreads();

#pragma unroll
    for (int i = 0; i < KI; i++) {
        int cur = i & 1;
        uint4 bnext[4];
        if (i + 1 < KI) {
            gloadA((i + 1) * 32);
#pragma unroll
            for (int ni = 0; ni < 4; ni++)
                bnext[ni] = *(const uint4*)(brow[ni] + (i + 1) * 32);
        }

        half8_t af[4];
#pragma unroll
        for (int mi = 0; mi < 4; mi++) {
            int row = wm + mi * 16 + l16;
            if constexpr (F32) {
                const float* pl = (const float*)&As[cur][0] + row * SROW + quad * 8;
                float4 x0 = *(const float4*)pl;
                float4 x1 = *(const float4*)(pl + 4);
                half8_t h;
                h[0] = (_Float16)x0.x; h[1] = (_Float16)x0.y;
                h[2] = (_Float16)x0.z; h[3] = (_Float16)x0.w;
                h[4] = (_Float16)x1.x; h[5] = (_Float16)x1.y;
                h[6] = (_Float16)x1.z; h[7] = (_Float16)x1.w;
                af[mi] = h;
            } else {
                af[mi] = *(const half8_t*)&As[cur][row * SROW + quad * 8];
            }
        }
#pragma unroll
        for (int mi = 0; mi < 4; mi++)
#pragma unroll
            for (int ni = 0; ni < 4; ni++)
                acc[mi][ni] = __builtin_amdgcn_mfma_f32_16x16x32_f16(
                    af[mi], *(half8_t*)&bcur[ni], acc[mi][ni], 0, 0, 0);

        if (i + 1 < KI) {
            sstore(cur ^ 1);
#pragma unroll
            for (int ni = 0; ni < 4; ni++) bcur[ni] = bnext[ni];
        }
        __syncthreads();
    }

    // write slice-major: c -> slice c>>5, within-slice c&31
#pragma unroll
    for (int mi = 0; mi < 4; mi++) {
#pragma unroll
        for (int r = 0; r < 4; r++) {
            int rr = row0 + wm + mi * 16 + quad * 4 + r;
            if (rr < M) {
#pragma unroll
                for (int ni = 0; ni < 4; ni++) {
                    int c = col0 + wn + ni * 16 + l16;
                    C[((size_t)(c >> 5) * NN + rr) * 32 + (c & 31)] =
                        __float2half(acc[mi][ni][r]);
                }
            }
        }
    }
}

// ---------------- sliced aggregation, degree-sorted order ----------------
// slice s = blockIdx.x % 8 (XCD round-robin -> 3.2MB slice fits 4MB L2).
// 4 lanes per node (8 ch), 64 nodes/block, nodes taken from degree-sorted perm
// so all 16 nodes in a wave have (near-)equal degree -> wave-uniform loops.
__device__ inline void fma8(float* acc, uint4 raw, float w) {
    const __half2* h = (const __half2*)&raw;
#pragma unroll
    for (int i = 0; i < 4; i++) {
        float2 f = __half22float2(h[i]);
        acc[2 * i]     += w * f.x;
        acc[2 * i + 1] += w * f.y;
    }
}

__global__ __launch_bounds__(256) void agg_selu(const __half* __restrict__ Ts,
                                                const float* __restrict__ dis,
                                                const int* __restrict__ off,
                                                const int* __restrict__ nbr,
                                                const __half* __restrict__ wgt,
                                                const int* __restrict__ perm,
                                                const float* __restrict__ bias,
                                                const __half* skip, __half* out) {
    int t = threadIdx.x;
    int s = blockIdx.x & 7;
    int gi = (blockIdx.x >> 3) * 64 + (t >> 2);
    int n = perm[gi];
    if (n < 0) return;  // padded tail
    int l4 = t & 3;
    int c4 = l4 * 8;
    const __half* Tsl = Ts + (size_t)s * NN * 32;
    float dn = dis[n];

    float acc[8];
#pragma unroll
    for (int i = 0; i < 8; i++) acc[i] = 0.f;
    fma8(acc, *(const uint4*)(Tsl + (size_t)n * 32 + c4), dn * dn);  // self-loop

    int s0 = off[n], s1 = off[n + 1];
    int base = s0;
    for (; base + 8 <= s1; base += 8) {
        int i0 = __builtin_nontemporal_load(&nbr[base + l4]);
        int i1 = __builtin_nontemporal_load(&nbr[base + 4 + l4]);
        unsigned short u0 = __builtin_nontemporal_load((const unsigned short*)&wgt[base + l4]);
        unsigned short u1 = __builtin_nontemporal_load((const unsigned short*)&wgt[base + 4 + l4]);
        __half h0 = *(__half*)&u0, h1 = *(__half*)&u1;
        float w0f = __half2float(h0), w1f = __half2float(h1);
        int id[8]; float ww[8];
#pragma unroll
        for (int j = 0; j < 4; j++) {
            id[j]     = __shfl(i0, j, 4); ww[j]     = __shfl(w0f, j, 4);
            id[4 + j] = __shfl(i1, j, 4); ww[4 + j] = __shfl(w1f, j, 4);
        }
        uint4 r[8];
#pragma unroll
        for (int j = 0; j < 8; j++)
            r[j] = *(const uint4*)(Tsl + (size_t)id[j] * 32 + c4);
#pragma unroll
        for (int j = 0; j < 8; j++) fma8(acc, r[j], ww[j]);
    }
    for (; base < s1; base += 4) {
        int cnt = min(4, s1 - base);
        int iv = 0; float wv = 0.f;
        if (l4 < cnt) {
            iv = __builtin_nontemporal_load(&nbr[base + l4]);
            unsigned short u = __builtin_nontemporal_load((const unsigned short*)&wgt[base + l4]);
            wv = __half2float(*(__half*)&u);
        }
        for (int j = 0; j < cnt; j++) {
            int idx = __shfl(iv, j, 4);
            float w = __shfl(wv, j, 4);
            fma8(acc, *(const uint4*)(Tsl + (size_t)idx * 32 + c4), w);
        }
    }

    const float scale = 1.0507009873554805f;
    const float alpha = 1.6732632423543772f;
    int cg = s * 32 + c4;  // global channel base
    float4 b0 = *(const float4*)(bias + cg);
    float4 b1 = *(const float4*)(bias + cg + 4);
    float bb[8] = {b0.x, b0.y, b0.z, b0.w, b1.x, b1.y, b1.z, b1.w};
    float sk8[8];
#pragma unroll
    for (int i = 0; i < 8; i++) sk8[i] = 0.f;
    if (skip) {
        uint4 raw = *(const uint4*)(skip + (size_t)n * HH + cg);
        const __half2* h = (const __half2*)&raw;
#pragma unroll
        for (int i = 0; i < 4; i++) {
            float2 f = __half22float2(h[i]);
            sk8[2 * i] = f.x; sk8[2 * i + 1] = f.y;
        }
    }
    _Float16 res[8];
#pragma unroll
    for (int i = 0; i < 8; i++) {
        float v = acc[i] + bb[i];
        float r = v > 0.f ? scale * v : scale * alpha * expm1f(v);
        res[i] = (_Float16)(r + sk8[i]);
    }
    *(uint4*)(out + (size_t)n * HH + cg) = *(uint4*)res;
}

// ---------------- assignment head via MFMA ----------------
__global__ __launch_bounds__(256) void assign_mfma(const __half* __restrict__ Hb,
                                                   const __half* __restrict__ WaT,
                                                   const float* __restrict__ ba,
                                                   const float* __restrict__ degf,
                                                   float* __restrict__ out_assign,
                                                   __half* __restrict__ out_f16,
                                                   float* __restrict__ scal) {
    int t = threadIdx.x;
    int wave = t >> 6, lane = t & 63, quad = lane >> 4, l16 = lane & 15;
    int nb = blockIdx.x * 256 + wave * 64;

    f32x4 acc[4] = {};
    const __half* bp = WaT + l16 * HH + quad * 8;
    const __half* ap[4];
#pragma unroll
    for (int mi = 0; mi < 4; mi++) {
        int r = nb + mi * 16 + l16;
        if (r >= NN) r = NN - 1;
        ap[mi] = Hb + (size_t)r * HH + quad * 8;
    }
#pragma unroll
    for (int s = 0; s < 8; s++) {
        half8_t bf = *(const half8_t*)(bp + s * 32);
#pragma unroll
        for (int mi = 0; mi < 4; mi++) {
            half8_t af = *(const half8_t*)(ap[mi] + s * 32);
            acc[mi] = __builtin_amdgcn_mfma_f32_16x16x32_f16(af, bf, acc[mi], 0, 0, 0);
        }
    }

    float myb = ba[l16];
    float lcs = 0.f, ldS = 0.f, lent = 0.f;
#pragma unroll
    for (int mi = 0; mi < 4; mi++) {
#pragma unroll
        for (int r = 0; r < 4; r++) {
            int node = nb + mi * 16 + quad * 4 + r;
            bool ok = node < NN;
            float logit = acc[mi][r] + myb;
            float mx = logit;
            for (int o = 1; o < 16; o <<= 1) mx = fmaxf(mx, __shfl_xor(mx, o, 16));
            float e = expf(logit - mx);
            float sum = e;
            for (int o = 1; o < 16; o <<= 1) sum += __shfl_xor(sum, o, 16);
            float a = e / sum;
            if (ok) {
                out_assign[(size_t)node * KK + l16] = a;
                out_f16[(size_t)node * KK + l16] = __float2half(a);
                lcs += a;
                ldS += degf[node] * a;
                lent += a * logf(a + 1e-8f);
            }
        }
    }
    lcs += __shfl_xor(lcs, 16); lcs += __shfl_xor(lcs, 32);
    ldS += __shfl_xor(ldS, 16); ldS += __shfl_xor(ldS, 32);
    for (int o = 32; o >= 1; o >>= 1) lent += __shfl_xor(lent, o);
    if (quad == 0) {
        atomicAdd(&scal[l16], lcs);
        atomicAdd(&scal[16 + l16], ldS);
    }
    if (lane == 0) atomicAdd(&scal[33], lent);
}

// ---------------- fused trace(S^T A S): 4 edges per thread, f16 assignments ----------------
__device__ inline float dot16h(const __half* a, const __half* b) {
    uint4 a0 = *(const uint4*)a, a1 = *(const uint4*)(a + 8);
    uint4 b0 = *(const uint4*)b, b1 = *(const uint4*)(b + 8);
    float p = 0.f;
    const __half2* xa = (const __half2*)&a0;
    const __half2* xb = (const __half2*)&b0;
#pragma unroll
    for (int i = 0; i < 4; i++) {
        float2 u = __half22float2(xa[i]), v = __half22float2(xb[i]);
        p += u.x * v.x + u.y * v.y;
    }
    xa = (const __half2*)&a1; xb = (const __half2*)&b1;
#pragma unroll
    for (int i = 0; i < 4; i++) {
        float2 u = __half22float2(xa[i]), v = __half22float2(xb[i]);
        p += u.x * v.x + u.y * v.y;
    }
    return p;
}

__global__ __launch_bounds__(256) void edge_trace(const int4* __restrict__ src4,
                                                  const int4* __restrict__ dst4,
                                                  const __half* __restrict__ Ah,
                                                  float* __restrict__ scal) {
    int e = blockIdx.x * blockDim.x + threadIdx.x;
    float p = 0.f;
    if (e < EE / 4) {
        int4 s = src4[e], d = dst4[e];
        p += dot16h(Ah + (size_t)s.x * KK, Ah + (size_t)d.x * KK);
        p += dot16h(Ah + (size_t)s.y * KK, Ah + (size_t)d.y * KK);
        p += dot16h(Ah + (size_t)s.z * KK, Ah + (size_t)d.z * KK);
        p += dot16h(Ah + (size_t)s.w * KK, Ah + (size_t)d.w * KK);
    }
    for (int o = 32; o >= 1; o >>= 1) p += __shfl_xor(p, o);
    __shared__ float sp;
    if (threadIdx.x == 0) sp = 0.f;
    __syncthreads();
    if ((threadIdx.x & 63) == 0) atomicAdd(&sp, p);
    __syncthreads();
    if (threadIdx.x == 0) atomicAdd(&scal[32], sp);
}

// ---------------- pooled partial: pool_acc[k][d] += sum_n a[n][k]*emb[n][d] ----------------
#define PCH 125
__global__ __launch_bounds__(256) void pooled_partial(const float* __restrict__ emb,
                                                      const float* __restrict__ assign,
                                                      float* __restrict__ pool_acc) {
    int d = blockIdx.x * 256 + threadIdx.x;
    int c0 = blockIdx.y * PCH;
    float acc[KK];
#pragma unroll
    for (int k = 0; k < KK; k++) acc[k] = 0.f;
    __shared__ float sa[PCH * KK];  // 8 KB
    {
        const float4* srcv = (const float4*)(assign + (size_t)c0 * KK);
        float4* dstv = (float4*)sa;
        for (int i = threadIdx.x; i < PCH * KK / 4; i += 256) dstv[i] = srcv[i];
    }
    __syncthreads();
    for (int j = 0; j < PCH; j++) {
        float ev = emb[(size_t)(c0 + j) * DD + d];
#pragma unroll
        for (int k4 = 0; k4 < 4; k4++) {
            float4 s4 = *(const float4*)&sa[j * KK + k4 * 4];
            acc[k4 * 4 + 0] += s4.x * ev;
            acc[k4 * 4 + 1] += s4.y * ev;
            acc[k4 * 4 + 2] += s4.z * ev;
            acc[k4 * 4 + 3] += s4.w * ev;
        }
    }
#pragma unroll
    for (int k = 0; k < KK; k++) atomicAdd(&pool_acc[k * DD + d], acc[k]);
}

// ---------------- finalize: pooled normalize + scalar losses ----------------
__global__ void finalize(const float* __restrict__ pool_acc, const float* __restrict__ scal,
                         float* __restrict__ out) {
    int bx = blockIdx.x, t = threadIdx.x;
    if (bx < 32) {
        int i = bx * 256 + t;  // 0..8191
        int k = i / DD;
        out[800000 + i] = pool_acc[i] / (scal[k] + 1e-8f);
    } else if (t == 0) {
        float cs2 = 0.f, ds2 = 0.f;
        for (int k = 0; k < KK; k++) {
            cs2 += scal[k] * scal[k];
            ds2 += scal[16 + k] * scal[16 + k];
        }
        float two_m = (float)EE;  // sum(degrees) == E, 2m == E
        float normalizer = ds2 / two_m;
        float trace = scal[32];
        float spectral = -(trace - (float)KK * normalizer) / two_m;
        float collapse = sqrtf(cs2) / (float)NN * 4.0f - 1.0f;  // sqrt(K)=4
        float entl = 0.1f * scal[33] / (float)NN;
        out[808192] = spectral;
        out[808193] = collapse;  // COLLAPSE_REG = 1.0
        out[808194] = spectral + collapse + entl;
        out[808195] = entl;
    }
}

extern "C" void kernel_launch(void* const* d_in, const int* in_sizes, int n_in,
                              void* d_out, int out_size, void* d_ws, size_t ws_size,
                              hipStream_t stream) {
    const float* emb = (const float*)d_in[0];
    const int* esrc  = (const int*)d_in[1];
    const int* edst  = (const int*)d_in[2];
    const float* W1  = (const float*)d_in[3];
    const float* b1  = (const float*)d_in[4];
    const float* W2  = (const float*)d_in[5];
    const float* b2  = (const float*)d_in[6];
    const float* Wa  = (const float*)d_in[7];
    const float* ba  = (const float*)d_in[8];
    float* out = (float*)d_out;

    // workspace layout (4B units unless noted) — total ~58 MB
    // zeroed prefix: indeg, outdeg, cur, pool_acc, scal, part, hist, cursor
    int* indeg      = (int*)d_ws;            // 50000
    int* outdeg     = indeg + 50000;         // 50000
    int* cur        = outdeg + 50000;        // 50000
    float* pool_acc = (float*)(cur + 50000); // 8192
    float* scal     = pool_acc + 8192;       // 64
    int* part       = (int*)(scal + 64);     // 256 (scan partials)
    int* hist       = part + 256;            // 512 (degree histogram -> offsets)
    int* cursor     = hist + 512;            // 512
    int* off        = cursor + 512;          // 50001 (+pad to 50004)
    int* perm       = off + 50004;           // 50048 (degree-sorted node order)
    int* nbr        = perm + NPAD;           // 800000
    float* dis      = (float*)(nbr + 800000);// 50000
    float* degf     = dis + 50000;           // 50000
    __half* wgt     = (__half*)(degf + 50000);   // 800000 f16 (1.6 MB)
    __half* Wt1     = wgt + 800000;              // 256*512 f16
    __half* Wt2     = Wt1 + 256 * 512;           // 256*256 f16
    __half* WaT     = Wt2 + 256 * 256;           // 16*256 f16
    __half* T       = WaT + 16 * 256;            // sliced [8][NN][32] f16 (25.6 MB)
    __half* Hb      = T + (size_t)NN * HH;       // row-major [NN][256] f16 (25.6 MB)
    __half* Ah      = T;  // f16 assignments alias T (dead after agg2)

    // zero atomically-accumulated prefix (158256 + 1024 hist/cursor + pad)
    zero_kernel<<<dim3(624), 256, 0, stream>>>((int*)d_ws, 159536);
    count_kernel<<<dim3(782), 256, 0, stream>>>((const int4*)esrc, (const int4*)edst,
                                                indeg, outdeg);

    // CSR offsets (3-phase scan, + dis/degf/hist in p1) + degree-sort perm
    scan_p1<<<dim3(NB_SCAN), 256, 0, stream>>>(indeg, part, NN, outdeg, dis, degf, hist);
    scan_p2<<<dim3(1), 256, 0, stream>>>(part, NB_SCAN, off + NN);
    scan_p3<<<dim3(NB_SCAN), 256, 0, stream>>>(indeg, part, off, NN);
    hist_scan<<<dim3(1), 256, 0, stream>>>(hist, perm);
    perm_scatter<<<dim3(NB_SCAN), 256, 0, stream>>>(indeg, hist, cursor, perm);
    scatter_kernel<<<dim3(782), 256, 0, stream>>>((const int4*)esrc, (const int4*)edst,
                                                  off, cur, dis, nbr, wgt);

    // weights -> f16 transposed (fused: W1, W2, Wa)
    transpose_w<<<dim3(784), 256, 0, stream>>>(W1, Wt1, W2, Wt2, Wa, WaT);

    // conv1: T = emb @ W1 (sliced) ; Hb = selu(Ahat*T + b1)
    mfma_gemm<float, DD><<<dim3(392, 2), 256, 0, stream>>>(emb, Wt1, T, NN);
    agg_selu<<<dim3(6256), 256, 0, stream>>>(T, dis, off, nbr, wgt, perm, b1, nullptr, Hb);

    // conv2: T = Hb @ W2 (sliced) ; Hb = selu(Ahat*T + b2) + Hb (skip, in place)
    mfma_gemm<__half, HH><<<dim3(392, 2), 256, 0, stream>>>(Hb, Wt2, T, NN);
    agg_selu<<<dim3(6256), 256, 0, stream>>>(T, dis, off, nbr, wgt, perm, b2, Hb, Hb);

    // head: assignments -> d_out[0..800000) (+f16 copy), loss partials
    assign_mfma<<<dim3(196), 256, 0, stream>>>(Hb, WaT, ba, degf, out, Ah, scal);
    edge_trace<<<dim3(782), 256, 0, stream>>>((const int4*)esrc, (const int4*)edst, Ah, scal);
    pooled_partial<<<dim3(2, 400), 256, 0, stream>>>(emb, out, pool_acc);
    finalize<<<dim3(33), 256, 0, stream>>>(pool_acc, scal, out);
}

// Round 9
// 618.081 us; speedup vs baseline: 1.5025x; 1.5025x over previous
//
#include <hip/hip_runtime.h>
#include <hip/hip_fp16.h>
#include <math.h>

#define NN 50000
#define EE 800000
#define DD 512
#define HH 256
#define KK 16
#define NB_SCAN 196  // ceil(NN/256)

typedef _Float16 half8_t __attribute__((ext_vector_type(8)));
typedef float f32x4 __attribute__((ext_vector_type(4)));

// ---------------- utility ----------------
__global__ void zero_kernel(int* __restrict__ p, int n) {
    int i = blockIdx.x * blockDim.x + threadIdx.x;
    if (i < n) p[i] = 0;
}

__global__ void count_kernel(const int4* __restrict__ src4, const int4* __restrict__ dst4,
                             int* __restrict__ indeg, int* __restrict__ outdeg) {
    int e = blockIdx.x * blockDim.x + threadIdx.x;
    if (e < EE / 4) {
        int4 s = src4[e], d = dst4[e];
        atomicAdd(&outdeg[s.x], 1); atomicAdd(&outdeg[s.y], 1);
        atomicAdd(&outdeg[s.z], 1); atomicAdd(&outdeg[s.w], 1);
        atomicAdd(&indeg[d.x], 1);  atomicAdd(&indeg[d.y], 1);
        atomicAdd(&indeg[d.z], 1);  atomicAdd(&indeg[d.w], 1);
    }
}

// ---------------- 3-phase multi-block exclusive scan (+node_prep fused in p1) ----------------
__global__ void scan_p1(const int* __restrict__ in, int* __restrict__ part, int n,
                        const int* __restrict__ outdeg, float* __restrict__ dis,
                        float* __restrict__ degf) {
    __shared__ int tile[256];
    int t = threadIdx.x;
    int i = blockIdx.x * 256 + t;
    int v = (i < n) ? in[i] : 0;
    tile[t] = v;
    if (i < n) {
        dis[i]  = 1.0f / sqrtf(1.0f + (float)v);
        degf[i] = (float)outdeg[i];
    }
    __syncthreads();
    for (int o = 128; o > 0; o >>= 1) {
        if (t < o) tile[t] += tile[t + o];
        __syncthreads();
    }
    if (t == 0) part[blockIdx.x] = tile[0];
}

__global__ void scan_p2(int* __restrict__ part, int nb, int* __restrict__ off_end) {
    __shared__ int tile[256];
    int t = threadIdx.x;
    int v = (t < nb) ? part[t] : 0;
    tile[t] = v;
    __syncthreads();
    for (int o = 1; o < 256; o <<= 1) {
        int x = (t >= o) ? tile[t - o] : 0;
        __syncthreads();
        tile[t] += x;
        __syncthreads();
    }
    if (t < nb) part[t] = tile[t] - v;  // exclusive base per block
    if (t == 255) *off_end = tile[255];
}

__global__ void scan_p3(const int* __restrict__ in, const int* __restrict__ part,
                        int* __restrict__ out, int n) {
    __shared__ int tile[256];
    int t = threadIdx.x;
    int i = blockIdx.x * 256 + t;
    int v = (i < n) ? in[i] : 0;
    tile[t] = v;
    __syncthreads();
    for (int o = 1; o < 256; o <<= 1) {
        int x = (t >= o) ? tile[t - o] : 0;
        __syncthreads();
        tile[t] += x;
        __syncthreads();
    }
    if (i < n) out[i] = part[blockIdx.x] + tile[t] - v;
}

// scatter edges into dst-CSR; also precompute edge weight w = dis[src]*dis[dst] (f16)
__global__ void scatter_kernel(const int4* __restrict__ src4, const int4* __restrict__ dst4,
                               const int* __restrict__ off, int* __restrict__ cur,
                               const float* __restrict__ dis,
                               int* __restrict__ nbr, __half* __restrict__ wgt) {
    int e = blockIdx.x * blockDim.x + threadIdx.x;
    if (e < EE / 4) {
        int4 s = src4[e], d = dst4[e];
        int p, q;
        p = atomicAdd(&cur[d.x], 1); q = off[d.x] + p;
        nbr[q] = s.x; wgt[q] = __float2half(dis[s.x] * dis[d.x]);
        p = atomicAdd(&cur[d.y], 1); q = off[d.y] + p;
        nbr[q] = s.y; wgt[q] = __float2half(dis[s.y] * dis[d.y]);
        p = atomicAdd(&cur[d.z], 1); q = off[d.z] + p;
        nbr[q] = s.z; wgt[q] = __float2half(dis[s.z] * dis[d.z]);
        p = atomicAdd(&cur[d.w], 1); q = off[d.w] + p;
        nbr[q] = s.w; wgt[q] = __float2half(dis[s.w] * dis[d.w]);
    }
}

// ---------------- fused weight transpose + f16 convert (W1, W2, Wa) ----------------
__global__ void transpose_w(const float* __restrict__ W1, __half* __restrict__ Wt1,
                            const float* __restrict__ W2, __half* __restrict__ Wt2,
                            const float* __restrict__ Wa, __half* __restrict__ WaT) {
    int i = blockIdx.x * 256 + threadIdx.x;
    if (i < DD * HH) {
        int k = i / HH, n = i % HH;
        Wt1[(size_t)n * DD + k] = __float2half(W1[i]);
    } else if (i < DD * HH + HH * HH) {
        int j = i - DD * HH;
        int k = j / HH, n = j % HH;
        Wt2[(size_t)n * HH + k] = __float2half(W2[j]);
    } else if (i < DD * HH + HH * HH + HH * KK) {
        int j = i - DD * HH - HH * HH;
        int k = j / KK, n = j % KK;
        WaT[n * HH + k] = __float2half(Wa[j]);
    }
}

// ---------------- no-LDS MFMA f16 GEMM: C[M,256] = A[M,KDIM] @ Wt[256,KDIM]^T ----------------
// Block tile 128x128, 4 waves x (64x64), 16x16x32 mfma. A and B fragments loaded
// directly from global (B is 256KB L2-resident; in-block A reuse is only 2x and
// L1/L2 absorb it). Zero barriers; depth-1 register pipeline; fully unrolled K.
__device__ inline half8_t loadfrag(const float* p) {
    float4 x0 = *(const float4*)p;
    float4 x1 = *(const float4*)(p + 4);
    half8_t h;
    h[0] = (_Float16)x0.x; h[1] = (_Float16)x0.y;
    h[2] = (_Float16)x0.z; h[3] = (_Float16)x0.w;
    h[4] = (_Float16)x1.x; h[5] = (_Float16)x1.y;
    h[6] = (_Float16)x1.z; h[7] = (_Float16)x1.w;
    return h;
}
__device__ inline half8_t loadfrag(const __half* p) { return *(const half8_t*)p; }

template <typename TA, int KDIM>
__global__ __launch_bounds__(256) void mfma_gemm(const TA* __restrict__ A,
                                                 const __half* __restrict__ Bt,
                                                 __half* __restrict__ C, int M) {
    constexpr int KI = KDIM / 32;
    int t = threadIdx.x;
    int wave = t >> 6, lane = t & 63, quad = lane >> 4, l16 = lane & 15;
    int row0 = blockIdx.x * 128, col0 = blockIdx.y * 128;
    int wm = (wave & 1) * 64, wn = (wave >> 1) * 64;

    const TA* ap[4];
    const __half* bp[4];
#pragma unroll
    for (int mi = 0; mi < 4; mi++) {
        int r = row0 + wm + mi * 16 + l16;
        if (r >= M) r = M - 1;  // clamp; clamped rows are never stored
        ap[mi] = A + (size_t)r * KDIM + quad * 8;
    }
#pragma unroll
    for (int ni = 0; ni < 4; ni++)
        bp[ni] = Bt + (size_t)(col0 + wn + ni * 16 + l16) * KDIM + quad * 8;

    f32x4 acc[4][4] = {};
    half8_t af[4], bf[4], afn[4], bfn[4];
#pragma unroll
    for (int mi = 0; mi < 4; mi++) af[mi] = loadfrag(ap[mi]);
#pragma unroll
    for (int ni = 0; ni < 4; ni++) bf[ni] = loadfrag(bp[ni]);

#pragma unroll
    for (int i = 0; i < KI; i++) {
        if (i + 1 < KI) {
#pragma unroll
            for (int mi = 0; mi < 4; mi++) afn[mi] = loadfrag(ap[mi] + (i + 1) * 32);
#pragma unroll
            for (int ni = 0; ni < 4; ni++) bfn[ni] = loadfrag(bp[ni] + (i + 1) * 32);
        }
#pragma unroll
        for (int mi = 0; mi < 4; mi++)
#pragma unroll
            for (int ni = 0; ni < 4; ni++)
                acc[mi][ni] = __builtin_amdgcn_mfma_f32_16x16x32_f16(
                    af[mi], bf[ni], acc[mi][ni], 0, 0, 0);
        if (i + 1 < KI) {
#pragma unroll
            for (int mi = 0; mi < 4; mi++) af[mi] = afn[mi];
#pragma unroll
            for (int ni = 0; ni < 4; ni++) bf[ni] = bfn[ni];
        }
    }

    // row-major C write: reg r -> row=quad*4+r, col=l16
#pragma unroll
    for (int mi = 0; mi < 4; mi++) {
#pragma unroll
        for (int r = 0; r < 4; r++) {
            int rr = row0 + wm + mi * 16 + quad * 4 + r;
            if (rr < M) {
#pragma unroll
                for (int ni = 0; ni < 4; ni++) {
                    C[(size_t)rr * HH + col0 + wn + ni * 16 + l16] =
                        __float2half(acc[mi][ni][r]);
                }
            }
        }
    }
}

// ---------------- aggregation + bias + SELU (+optional skip) — round-6 structure ----------------
// Half-wave (32 lanes) per node, 8 ch/lane (16B loads), 8 nodes/block,
// precomputed f16 edge weights, x8 unroll with loads batched ahead of FMAs.
__device__ inline void fma8(float* acc, uint4 raw, float w) {
    const __half2* h = (const __half2*)&raw;
#pragma unroll
    for (int i = 0; i < 4; i++) {
        float2 f = __half22float2(h[i]);
        acc[2 * i]     += w * f.x;
        acc[2 * i + 1] += w * f.y;
    }
}

__global__ __launch_bounds__(256) void agg_selu(const __half* __restrict__ T,
                                                const float* __restrict__ dis,
                                                const int* __restrict__ off,
                                                const int* __restrict__ nbr,
                                                const __half* __restrict__ wgt,
                                                const float* __restrict__ bias,
                                                const __half* skip, __half* out) {
    int t = threadIdx.x;
    int l32 = t & 31;
    int n = blockIdx.x * 8 + (t >> 5);
    int c = l32 * 8;
    float dn = dis[n];

    float acc[8];
#pragma unroll
    for (int i = 0; i < 8; i++) acc[i] = 0.f;
    fma8(acc, *(const uint4*)(T + (size_t)n * HH + c), dn * dn);  // self-loop

    int s0 = off[n], s1 = off[n + 1];
    for (int base = s0; base < s1; base += 32) {
        int cnt = min(32, s1 - base);
        int sidv = 0; float wv = 0.f;
        if (l32 < cnt) {
            sidv = nbr[base + l32];
            wv = __half2float(wgt[base + l32]);
        }
        int j = 0;
        for (; j + 8 <= cnt; j += 8) {
            int a0 = __shfl(sidv, j, 32),     a1 = __shfl(sidv, j + 1, 32);
            int a2 = __shfl(sidv, j + 2, 32), a3 = __shfl(sidv, j + 3, 32);
            int a4 = __shfl(sidv, j + 4, 32), a5 = __shfl(sidv, j + 5, 32);
            int a6 = __shfl(sidv, j + 6, 32), a7 = __shfl(sidv, j + 7, 32);
            float w0 = __shfl(wv, j, 32),     w1 = __shfl(wv, j + 1, 32);
            float w2 = __shfl(wv, j + 2, 32), w3 = __shfl(wv, j + 3, 32);
            float w4 = __shfl(wv, j + 4, 32), w5 = __shfl(wv, j + 5, 32);
            float w6 = __shfl(wv, j + 6, 32), w7 = __shfl(wv, j + 7, 32);
            uint4 r0 = *(const uint4*)(T + (size_t)a0 * HH + c);
            uint4 r1 = *(const uint4*)(T + (size_t)a1 * HH + c);
            uint4 r2 = *(const uint4*)(T + (size_t)a2 * HH + c);
            uint4 r3 = *(const uint4*)(T + (size_t)a3 * HH + c);
            uint4 r4 = *(const uint4*)(T + (size_t)a4 * HH + c);
            uint4 r5 = *(const uint4*)(T + (size_t)a5 * HH + c);
            uint4 r6 = *(const uint4*)(T + (size_t)a6 * HH + c);
            uint4 r7 = *(const uint4*)(T + (size_t)a7 * HH + c);
            fma8(acc, r0, w0); fma8(acc, r1, w1);
            fma8(acc, r2, w2); fma8(acc, r3, w3);
            fma8(acc, r4, w4); fma8(acc, r5, w5);
            fma8(acc, r6, w6); fma8(acc, r7, w7);
        }
        for (; j < cnt; j++) {
            int s = __shfl(sidv, j, 32);
            float w = __shfl(wv, j, 32);
            fma8(acc, *(const uint4*)(T + (size_t)s * HH + c), w);
        }
    }

    const float scale = 1.0507009873554805f;
    const float alpha = 1.6732632423543772f;
    float4 b0 = *(const float4*)(bias + c);
    float4 b1 = *(const float4*)(bias + c + 4);
    float bb[8] = {b0.x, b0.y, b0.z, b0.w, b1.x, b1.y, b1.z, b1.w};
    float sk8[8];
#pragma unroll
    for (int i = 0; i < 8; i++) sk8[i] = 0.f;
    if (skip) {
        uint4 raw = *(const uint4*)(skip + (size_t)n * HH + c);
        const __half2* h = (const __half2*)&raw;
#pragma unroll
        for (int i = 0; i < 4; i++) {
            float2 f = __half22float2(h[i]);
            sk8[2 * i] = f.x; sk8[2 * i + 1] = f.y;
        }
    }
    _Float16 res[8];
#pragma unroll
    for (int i = 0; i < 8; i++) {
        float v = acc[i] + bb[i];
        float r = v > 0.f ? scale * v : scale * alpha * expm1f(v);
        res[i] = (_Float16)(r + sk8[i]);
    }
    *(uint4*)(out + (size_t)n * HH + c) = *(uint4*)res;
}

// ---------------- assignment head via MFMA ----------------
__global__ __launch_bounds__(256) void assign_mfma(const __half* __restrict__ Hb,
                                                   const __half* __restrict__ WaT,
                                                   const float* __restrict__ ba,
                                                   const float* __restrict__ degf,
                                                   float* __restrict__ out_assign,
                                                   __half* __restrict__ out_f16,
                                                   float* __restrict__ scal) {
    int t = threadIdx.x;
    int wave = t >> 6, lane = t & 63, quad = lane >> 4, l16 = lane & 15;
    int nb = blockIdx.x * 256 + wave * 64;

    f32x4 acc[4] = {};
    const __half* bp = WaT + l16 * HH + quad * 8;
    const __half* ap[4];
#pragma unroll
    for (int mi = 0; mi < 4; mi++) {
        int r = nb + mi * 16 + l16;
        if (r >= NN) r = NN - 1;
        ap[mi] = Hb + (size_t)r * HH + quad * 8;
    }
#pragma unroll
    for (int s = 0; s < 8; s++) {
        half8_t bf = *(const half8_t*)(bp + s * 32);
#pragma unroll
        for (int mi = 0; mi < 4; mi++) {
            half8_t af = *(const half8_t*)(ap[mi] + s * 32);
            acc[mi] = __builtin_amdgcn_mfma_f32_16x16x32_f16(af, bf, acc[mi], 0, 0, 0);
        }
    }

    float myb = ba[l16];
    float lcs = 0.f, ldS = 0.f, lent = 0.f;
#pragma unroll
    for (int mi = 0; mi < 4; mi++) {
#pragma unroll
        for (int r = 0; r < 4; r++) {
            int node = nb + mi * 16 + quad * 4 + r;
            bool ok = node < NN;
            float logit = acc[mi][r] + myb;
            float mx = logit;
            for (int o = 1; o < 16; o <<= 1) mx = fmaxf(mx, __shfl_xor(mx, o, 16));
            float e = expf(logit - mx);
            float sum = e;
            for (int o = 1; o < 16; o <<= 1) sum += __shfl_xor(sum, o, 16);
            float a = e / sum;
            if (ok) {
                out_assign[(size_t)node * KK + l16] = a;
                out_f16[(size_t)node * KK + l16] = __float2half(a);
                lcs += a;
                ldS += degf[node] * a;
                lent += a * logf(a + 1e-8f);
            }
        }
    }
    lcs += __shfl_xor(lcs, 16); lcs += __shfl_xor(lcs, 32);
    ldS += __shfl_xor(ldS, 16); ldS += __shfl_xor(ldS, 32);
    for (int o = 32; o >= 1; o >>= 1) lent += __shfl_xor(lent, o);
    if (quad == 0) {
        atomicAdd(&scal[l16], lcs);
        atomicAdd(&scal[16 + l16], ldS);
    }
    if (lane == 0) atomicAdd(&scal[33], lent);
}

// ---------------- fused trace(S^T A S): 4 edges per thread, f16 assignments ----------------
__device__ inline float dot16h(const __half* a, const __half* b) {
    uint4 a0 = *(const uint4*)a, a1 = *(const uint4*)(a + 8);
    uint4 b0 = *(const uint4*)b, b1 = *(const uint4*)(b + 8);
    float p = 0.f;
    const __half2* xa = (const __half2*)&a0;
    const __half2* xb = (const __half2*)&b0;
#pragma unroll
    for (int i = 0; i < 4; i++) {
        float2 u = __half22float2(xa[i]), v = __half22float2(xb[i]);
        p += u.x * v.x + u.y * v.y;
    }
    xa = (const __half2*)&a1; xb = (const __half2*)&b1;
#pragma unroll
    for (int i = 0; i < 4; i++) {
        float2 u = __half22float2(xa[i]), v = __half22float2(xb[i]);
        p += u.x * v.x + u.y * v.y;
    }
    return p;
}

__global__ __launch_bounds__(256) void edge_trace(const int4* __restrict__ src4,
                                                  const int4* __restrict__ dst4,
                                                  const __half* __restrict__ Ah,
                                                  float* __restrict__ scal) {
    int e = blockIdx.x * blockDim.x + threadIdx.x;
    float p = 0.f;
    if (e < EE / 4) {
        int4 s = src4[e], d = dst4[e];
        p += dot16h(Ah + (size_t)s.x * KK, Ah + (size_t)d.x * KK);
        p += dot16h(Ah + (size_t)s.y * KK, Ah + (size_t)d.y * KK);
        p += dot16h(Ah + (size_t)s.z * KK, Ah + (size_t)d.z * KK);
        p += dot16h(Ah + (size_t)s.w * KK, Ah + (size_t)d.w * KK);
    }
    for (int o = 32; o >= 1; o >>= 1) p += __shfl_xor(p, o);
    __shared__ float sp;
    if (threadIdx.x == 0) sp = 0.f;
    __syncthreads();
    if ((threadIdx.x & 63) == 0) atomicAdd(&sp, p);
    __syncthreads();
    if (threadIdx.x == 0) atomicAdd(&scal[32], sp);
}

// ---------------- pooled partial: pool_acc[k][d] += sum_n a[n][k]*emb[n][d] ----------------
#define PCH 125
__global__ __launch_bounds__(256) void pooled_partial(const float* __restrict__ emb,
                                                      const float* __restrict__ assign,
                                                      float* __restrict__ pool_acc) {
    int d = blockIdx.x * 256 + threadIdx.x;
    int c0 = blockIdx.y * PCH;
    float acc[KK];
#pragma unroll
    for (int k = 0; k < KK; k++) acc[k] = 0.f;
    __shared__ float sa[PCH * KK];  // 8 KB
    {
        const float4* srcv = (const float4*)(assign + (size_t)c0 * KK);
        float4* dstv = (float4*)sa;
        for (int i = threadIdx.x; i < PCH * KK / 4; i += 256) dstv[i] = srcv[i];
    }
    __syncthreads();
    for (int j = 0; j < PCH; j++) {
        float ev = emb[(size_t)(c0 + j) * DD + d];
#pragma unroll
        for (int k4 = 0; k4 < 4; k4++) {
            float4 s4 = *(const float4*)&sa[j * KK + k4 * 4];
            acc[k4 * 4 + 0] += s4.x * ev;
            acc[k4 * 4 + 1] += s4.y * ev;
            acc[k4 * 4 + 2] += s4.z * ev;
            acc[k4 * 4 + 3] += s4.w * ev;
        }
    }
#pragma unroll
    for (int k = 0; k < KK; k++) atomicAdd(&pool_acc[k * DD + d], acc[k]);
}

// ---------------- finalize: pooled normalize + scalar losses ----------------
__global__ void finalize(const float* __restrict__ pool_acc, const float* __restrict__ scal,
                         float* __restrict__ out) {
    int bx = blockIdx.x, t = threadIdx.x;
    if (bx < 32) {
        int i = bx * 256 + t;  // 0..8191
        int k = i / DD;
        out[800000 + i] = pool_acc[i] / (scal[k] + 1e-8f);
    } else if (t == 0) {
        float cs2 = 0.f, ds2 = 0.f;
        for (int k = 0; k < KK; k++) {
            cs2 += scal[k] * scal[k];
            ds2 += scal[16 + k] * scal[16 + k];
        }
        float two_m = (float)EE;  // sum(degrees) == E, 2m == E
        float normalizer = ds2 / two_m;
        float trace = scal[32];
        float spectral = -(trace - (float)KK * normalizer) / two_m;
        float collapse = sqrtf(cs2) / (float)NN * 4.0f - 1.0f;  // sqrt(K)=4
        float entl = 0.1f * scal[33] / (float)NN;
        out[808192] = spectral;
        out[808193] = collapse;  // COLLAPSE_REG = 1.0
        out[808194] = spectral + collapse + entl;
        out[808195] = entl;
    }
}

extern "C" void kernel_launch(void* const* d_in, const int* in_sizes, int n_in,
                              void* d_out, int out_size, void* d_ws, size_t ws_size,
                              hipStream_t stream) {
    const float* emb = (const float*)d_in[0];
    const int* esrc  = (const int*)d_in[1];
    const int* edst  = (const int*)d_in[2];
    const float* W1  = (const float*)d_in[3];
    const float* b1  = (const float*)d_in[4];
    const float* W2  = (const float*)d_in[5];
    const float* b2  = (const float*)d_in[6];
    const float* Wa  = (const float*)d_in[7];
    const float* ba  = (const float*)d_in[8];
    float* out = (float*)d_out;

    // workspace layout (4B units unless noted) — total ~58 MB
    int* indeg      = (int*)d_ws;            // 50000
    int* outdeg     = indeg + 50000;         // 50000
    int* cur        = outdeg + 50000;        // 50000
    float* pool_acc = (float*)(cur + 50000); // 8192
    float* scal     = pool_acc + 8192;       // 64
    int* part       = (int*)(scal + 64);     // 256 (scan partials)
    int* off        = part + 256;            // 50001 (+pad to 50004)
    int* nbr        = off + 50004;           // 800000
    float* dis      = (float*)(nbr + 800000);// 50000
    float* degf     = dis + 50000;           // 50000
    __half* wgt     = (__half*)(degf + 50000);   // 800000 f16 (1.6 MB)
    __half* Wt1     = wgt + 800000;              // 256*512 f16
    __half* Wt2     = Wt1 + 256 * 512;           // 256*256 f16
    __half* WaT     = Wt2 + 256 * 256;           // 16*256 f16
    __half* T       = WaT + 16 * 256;            // row-major [NN][256] f16 (25.6 MB)
    __half* Hb      = T + (size_t)NN * HH;       // row-major [NN][256] f16 (25.6 MB)
    __half* Ah      = T;  // f16 assignments alias T (dead after agg2)

    // zero the atomically-accumulated region: indeg/outdeg/cur/pool_acc/scal
    zero_kernel<<<dim3(619), 256, 0, stream>>>((int*)d_ws, 158256);
    count_kernel<<<dim3(782), 256, 0, stream>>>((const int4*)esrc, (const int4*)edst,
                                                indeg, outdeg);

    // CSR offsets: 3-phase scan (+ dis/degf in p1)
    scan_p1<<<dim3(NB_SCAN), 256, 0, stream>>>(indeg, part, NN, outdeg, dis, degf);
    scan_p2<<<dim3(1), 256, 0, stream>>>(part, NB_SCAN, off + NN);
    scan_p3<<<dim3(NB_SCAN), 256, 0, stream>>>(indeg, part, off, NN);
    scatter_kernel<<<dim3(782), 256, 0, stream>>>((const int4*)esrc, (const int4*)edst,
                                                  off, cur, dis, nbr, wgt);

    // weights -> f16 transposed (fused: W1, W2, Wa)
    transpose_w<<<dim3(784), 256, 0, stream>>>(W1, Wt1, W2, Wt2, Wa, WaT);

    // conv1: T = emb @ W1 ; Hb = selu(Ahat*T + b1)
    mfma_gemm<float, DD><<<dim3(392, 2), 256, 0, stream>>>(emb, Wt1, T, NN);
    agg_selu<<<dim3(6250), 256, 0, stream>>>(T, dis, off, nbr, wgt, b1, nullptr, Hb);

    // conv2: T = Hb @ W2 ; Hb = selu(Ahat*T + b2) + Hb (skip, in place)
    mfma_gemm<__half, HH><<<dim3(392, 2), 256, 0, stream>>>(Hb, Wt2, T, NN);
    agg_selu<<<dim3(6250), 256, 0, stream>>>(T, dis, off, nbr, wgt, b2, Hb, Hb);

    // head: assignments -> d_out[0..800000) (+f16 copy), loss partials
    assign_mfma<<<dim3(196), 256, 0, stream>>>(Hb, WaT, ba, degf, out, Ah, scal);
    edge_trace<<<dim3(782), 256, 0, stream>>>((const int4*)esrc, (const int4*)edst, Ah, scal);
    pooled_partial<<<dim3(2, 400), 256, 0, stream>>>(emb, out, pool_acc);
    finalize<<<dim3(33), 256, 0, stream>>>(pool_acc, scal, out);
}

// Round 10
// 563.934 us; speedup vs baseline: 1.6468x; 1.0960x over previous
//
#include <hip/hip_runtime.h>
#include <hip/hip_fp16.h>
#include <math.h>

#define NN 50000
#define EE 800000
#define DD 512
#define HH 256
#define KK 16
#define NB_SCAN 196  // ceil(NN/256)

typedef _Float16 half8_t __attribute__((ext_vector_type(8)));
typedef float f32x4 __attribute__((ext_vector_type(4)));

// ---------------- utility ----------------
__global__ void zero_kernel(int* __restrict__ p, int n) {
    int i = blockIdx.x * blockDim.x + threadIdx.x;
    if (i < n) p[i] = 0;
}

__global__ void count_kernel(const int4* __restrict__ src4, const int4* __restrict__ dst4,
                             int* __restrict__ indeg, int* __restrict__ outdeg) {
    int e = blockIdx.x * blockDim.x + threadIdx.x;
    if (e < EE / 4) {
        int4 s = src4[e], d = dst4[e];
        atomicAdd(&outdeg[s.x], 1); atomicAdd(&outdeg[s.y], 1);
        atomicAdd(&outdeg[s.z], 1); atomicAdd(&outdeg[s.w], 1);
        atomicAdd(&indeg[d.x], 1);  atomicAdd(&indeg[d.y], 1);
        atomicAdd(&indeg[d.z], 1);  atomicAdd(&indeg[d.w], 1);
    }
}

// ---------------- 3-phase multi-block exclusive scan (+node_prep fused in p1) ----------------
__global__ void scan_p1(const int* __restrict__ in, int* __restrict__ part, int n,
                        const int* __restrict__ outdeg, float* __restrict__ dis,
                        float* __restrict__ degf) {
    __shared__ int tile[256];
    int t = threadIdx.x;
    int i = blockIdx.x * 256 + t;
    int v = (i < n) ? in[i] : 0;
    tile[t] = v;
    if (i < n) {
        dis[i]  = 1.0f / sqrtf(1.0f + (float)v);
        degf[i] = (float)outdeg[i];
    }
    __syncthreads();
    for (int o = 128; o > 0; o >>= 1) {
        if (t < o) tile[t] += tile[t + o];
        __syncthreads();
    }
    if (t == 0) part[blockIdx.x] = tile[0];
}

__global__ void scan_p2(int* __restrict__ part, int nb, int* __restrict__ off_end) {
    __shared__ int tile[256];
    int t = threadIdx.x;
    int v = (t < nb) ? part[t] : 0;
    tile[t] = v;
    __syncthreads();
    for (int o = 1; o < 256; o <<= 1) {
        int x = (t >= o) ? tile[t - o] : 0;
        __syncthreads();
        tile[t] += x;
        __syncthreads();
    }
    if (t < nb) part[t] = tile[t] - v;  // exclusive base per block
    if (t == 255) *off_end = tile[255];
}

__global__ void scan_p3(const int* __restrict__ in, const int* __restrict__ part,
                        int* __restrict__ out, int n) {
    __shared__ int tile[256];
    int t = threadIdx.x;
    int i = blockIdx.x * 256 + t;
    int v = (i < n) ? in[i] : 0;
    tile[t] = v;
    __syncthreads();
    for (int o = 1; o < 256; o <<= 1) {
        int x = (t >= o) ? tile[t - o] : 0;
        __syncthreads();
        tile[t] += x;
        __syncthreads();
    }
    if (i < n) out[i] = part[blockIdx.x] + tile[t] - v;
}

// scatter edges into dst-CSR; also precompute edge weight w = dis[src]*dis[dst] (f16)
__global__ void scatter_kernel(const int4* __restrict__ src4, const int4* __restrict__ dst4,
                               const int* __restrict__ off, int* __restrict__ cur,
                               const float* __restrict__ dis,
                               int* __restrict__ nbr, __half* __restrict__ wgt) {
    int e = blockIdx.x * blockDim.x + threadIdx.x;
    if (e < EE / 4) {
        int4 s = src4[e], d = dst4[e];
        int p, q;
        p = atomicAdd(&cur[d.x], 1); q = off[d.x] + p;
        nbr[q] = s.x; wgt[q] = __float2half(dis[s.x] * dis[d.x]);
        p = atomicAdd(&cur[d.y], 1); q = off[d.y] + p;
        nbr[q] = s.y; wgt[q] = __float2half(dis[s.y] * dis[d.y]);
        p = atomicAdd(&cur[d.z], 1); q = off[d.z] + p;
        nbr[q] = s.z; wgt[q] = __float2half(dis[s.z] * dis[d.z]);
        p = atomicAdd(&cur[d.w], 1); q = off[d.w] + p;
        nbr[q] = s.w; wgt[q] = __float2half(dis[s.w] * dis[d.w]);
    }
}

// ---------------- fused weight transpose + f16 convert (W1, W2, Wa) ----------------
__global__ void transpose_w(const float* __restrict__ W1, __half* __restrict__ Wt1,
                            const float* __restrict__ W2, __half* __restrict__ Wt2,
                            const float* __restrict__ Wa, __half* __restrict__ WaT) {
    int i = blockIdx.x * 256 + threadIdx.x;
    if (i < DD * HH) {
        int k = i / HH, n = i % HH;
        Wt1[(size_t)n * DD + k] = __float2half(W1[i]);
    } else if (i < DD * HH + HH * HH) {
        int j = i - DD * HH;
        int k = j / HH, n = j % HH;
        Wt2[(size_t)n * HH + k] = __float2half(W2[j]);
    } else if (i < DD * HH + HH * HH + HH * KK) {
        int j = i - DD * HH - HH * HH;
        int k = j / KK, n = j % KK;
        WaT[n * HH + k] = __float2half(Wa[j]);
    }
}

// ---------------- MFMA f16 GEMM: C[M,256] = A[M,KDIM] @ Wt[256,KDIM]^T ----------------
// 128x128 block tile, 4 waves x (64x64), 16x16x32 mfma, K-step 32.
// A staged to double-buffered f16 LDS (f32 input converted during staging);
// B fragments direct from global (256KB, L2-resident). Register prefetch of
// next A-stage + B-frags overlaps MFMA; one barrier per K-iter.
// LDS row stride 40 halves (80B): 16B-aligned, 2-way bank alias (free).
template <typename TA, int KDIM>
__global__ __launch_bounds__(256) void mfma_gemm(const TA* __restrict__ A,
                                                 const __half* __restrict__ Bt,
                                                 __half* __restrict__ C, int M) {
    constexpr bool F32 = sizeof(TA) == 4;
    constexpr int KI = KDIM / 32;
    __shared__ _Float16 As[2][128 * 40];  // 20.5 KB

    int t = threadIdx.x;
    int wave = t >> 6, lane = t & 63, quad = lane >> 4, l16 = lane & 15;
    int row0 = blockIdx.x * 128, col0 = blockIdx.y * 128;
    int wm = (wave & 1) * 64, wn = (wave >> 1) * 64;
    int sr = t >> 1, sk = (t & 1) * 16;  // staging: row 0..127, k-offset 0/16

    int gr = row0 + sr;
    if (gr >= M) gr = M - 1;  // clamp: OOB rows stage duplicate data, never stored
    const TA* aptr = A + (size_t)gr * KDIM + sk;

    const __half* brow[4];
#pragma unroll
    for (int ni = 0; ni < 4; ni++)
        brow[ni] = Bt + (size_t)(col0 + wn + ni * 16 + l16) * KDIM + quad * 8;

    f32x4 acc[4][4] = {};
    uint4 areg[2], bcur[4];

    auto gloadA = [&](int k0, uint4* o) {
        if constexpr (F32) {
            float4 x0 = *(const float4*)(aptr + k0);
            float4 x1 = *(const float4*)(aptr + k0 + 4);
            float4 x2 = *(const float4*)(aptr + k0 + 8);
            float4 x3 = *(const float4*)(aptr + k0 + 12);
            _Float16 h[16];
            h[0] = (_Float16)x0.x;  h[1] = (_Float16)x0.y;
            h[2] = (_Float16)x0.z;  h[3] = (_Float16)x0.w;
            h[4] = (_Float16)x1.x;  h[5] = (_Float16)x1.y;
            h[6] = (_Float16)x1.z;  h[7] = (_Float16)x1.w;
            h[8] = (_Float16)x2.x;  h[9] = (_Float16)x2.y;
            h[10] = (_Float16)x2.z; h[11] = (_Float16)x2.w;
            h[12] = (_Float16)x3.x; h[13] = (_Float16)x3.y;
            h[14] = (_Float16)x3.z; h[15] = (_Float16)x3.w;
            o[0] = *(uint4*)h;
            o[1] = *(uint4*)(h + 8);
        } else {
            o[0] = *(const uint4*)(aptr + k0);
            o[1] = *(const uint4*)(aptr + k0 + 8);
        }
    };
    auto sstore = [&](int buf, const uint4* v) {
        *(uint4*)&As[buf][sr * 40 + sk] = v[0];
        *(uint4*)&As[buf][sr * 40 + sk + 8] = v[1];
    };

    gloadA(0, areg);
#pragma unroll
    for (int ni = 0; ni < 4; ni++) bcur[ni] = *(const uint4*)(brow[ni]);
    sstore(0, areg);
    __syncthreads();

#pragma unroll
    for (int i = 0; i < KI; i++) {
        int cur = i & 1;
        uint4 anext[2], bnext[4];
        if (i + 1 < KI) {
            gloadA((i + 1) * 32, anext);
#pragma unroll
            for (int ni = 0; ni < 4; ni++)
                bnext[ni] = *(const uint4*)(brow[ni] + (i + 1) * 32);
        }

        half8_t af[4];
#pragma unroll
        for (int mi = 0; mi < 4; mi++)
            af[mi] = *(const half8_t*)&As[cur][(wm + mi * 16 + l16) * 40 + quad * 8];
#pragma unroll
        for (int mi = 0; mi < 4; mi++)
#pragma unroll
            for (int ni = 0; ni < 4; ni++)
                acc[mi][ni] = __builtin_amdgcn_mfma_f32_16x16x32_f16(
                    af[mi], *(half8_t*)&bcur[ni], acc[mi][ni], 0, 0, 0);

        if (i + 1 < KI) {
            sstore(cur ^ 1, anext);
#pragma unroll
            for (int ni = 0; ni < 4; ni++) bcur[ni] = bnext[ni];
        }
        __syncthreads();
    }

    // row-major C write: reg r -> row=quad*4+r, col=l16
#pragma unroll
    for (int mi = 0; mi < 4; mi++) {
#pragma unroll
        for (int r = 0; r < 4; r++) {
            int rr = row0 + wm + mi * 16 + quad * 4 + r;
            if (rr < M) {
#pragma unroll
                for (int ni = 0; ni < 4; ni++) {
                    C[(size_t)rr * HH + col0 + wn + ni * 16 + l16] =
                        __float2half(acc[mi][ni][r]);
                }
            }
        }
    }
}

// ---------------- aggregation + bias + SELU (+optional skip) ----------------
// Half-wave (32 lanes) per node, 8 ch/lane (16B loads), 8 nodes/block,
// precomputed f16 edge weights, x8 unroll with loads batched ahead of FMAs.
__device__ inline void fma8(float* acc, uint4 raw, float w) {
    const __half2* h = (const __half2*)&raw;
#pragma unroll
    for (int i = 0; i < 4; i++) {
        float2 f = __half22float2(h[i]);
        acc[2 * i]     += w * f.x;
        acc[2 * i + 1] += w * f.y;
    }
}

__global__ __launch_bounds__(256) void agg_selu(const __half* __restrict__ T,
                                                const float* __restrict__ dis,
                                                const int* __restrict__ off,
                                                const int* __restrict__ nbr,
                                                const __half* __restrict__ wgt,
                                                const float* __restrict__ bias,
                                                const __half* skip, __half* out) {
    int t = threadIdx.x;
    int l32 = t & 31;
    int n = blockIdx.x * 8 + (t >> 5);
    int c = l32 * 8;
    float dn = dis[n];

    float acc[8];
#pragma unroll
    for (int i = 0; i < 8; i++) acc[i] = 0.f;
    fma8(acc, *(const uint4*)(T + (size_t)n * HH + c), dn * dn);  // self-loop

    int s0 = off[n], s1 = off[n + 1];
    for (int base = s0; base < s1; base += 32) {
        int cnt = min(32, s1 - base);
        int sidv = 0; float wv = 0.f;
        if (l32 < cnt) {
            sidv = nbr[base + l32];
            wv = __half2float(wgt[base + l32]);
        }
        int j = 0;
        for (; j + 8 <= cnt; j += 8) {
            int a0 = __shfl(sidv, j, 32),     a1 = __shfl(sidv, j + 1, 32);
            int a2 = __shfl(sidv, j + 2, 32), a3 = __shfl(sidv, j + 3, 32);
            int a4 = __shfl(sidv, j + 4, 32), a5 = __shfl(sidv, j + 5, 32);
            int a6 = __shfl(sidv, j + 6, 32), a7 = __shfl(sidv, j + 7, 32);
            float w0 = __shfl(wv, j, 32),     w1 = __shfl(wv, j + 1, 32);
            float w2 = __shfl(wv, j + 2, 32), w3 = __shfl(wv, j + 3, 32);
            float w4 = __shfl(wv, j + 4, 32), w5 = __shfl(wv, j + 5, 32);
            float w6 = __shfl(wv, j + 6, 32), w7 = __shfl(wv, j + 7, 32);
            uint4 r0 = *(const uint4*)(T + (size_t)a0 * HH + c);
            uint4 r1 = *(const uint4*)(T + (size_t)a1 * HH + c);
            uint4 r2 = *(const uint4*)(T + (size_t)a2 * HH + c);
            uint4 r3 = *(const uint4*)(T + (size_t)a3 * HH + c);
            uint4 r4 = *(const uint4*)(T + (size_t)a4 * HH + c);
            uint4 r5 = *(const uint4*)(T + (size_t)a5 * HH + c);
            uint4 r6 = *(const uint4*)(T + (size_t)a6 * HH + c);
            uint4 r7 = *(const uint4*)(T + (size_t)a7 * HH + c);
            fma8(acc, r0, w0); fma8(acc, r1, w1);
            fma8(acc, r2, w2); fma8(acc, r3, w3);
            fma8(acc, r4, w4); fma8(acc, r5, w5);
            fma8(acc, r6, w6); fma8(acc, r7, w7);
        }
        for (; j < cnt; j++) {
            int s = __shfl(sidv, j, 32);
            float w = __shfl(wv, j, 32);
            fma8(acc, *(const uint4*)(T + (size_t)s * HH + c), w);
        }
    }

    const float scale = 1.0507009873554805f;
    const float alpha = 1.6732632423543772f;
    float4 b0 = *(const float4*)(bias + c);
    float4 b1 = *(const float4*)(bias + c + 4);
    float bb[8] = {b0.x, b0.y, b0.z, b0.w, b1.x, b1.y, b1.z, b1.w};
    float sk8[8];
#pragma unroll
    for (int i = 0; i < 8; i++) sk8[i] = 0.f;
    if (skip) {
        uint4 raw = *(const uint4*)(skip + (size_t)n * HH + c);
        const __half2* h = (const __half2*)&raw;
#pragma unroll
        for (int i = 0; i < 4; i++) {
            float2 f = __half22float2(h[i]);
            sk8[2 * i] = f.x; sk8[2 * i + 1] = f.y;
        }
    }
    _Float16 res[8];
#pragma unroll
    for (int i = 0; i < 8; i++) {
        float v = acc[i] + bb[i];
        float r = v > 0.f ? scale * v : scale * alpha * expm1f(v);
        res[i] = (_Float16)(r + sk8[i]);
    }
    *(uint4*)(out + (size_t)n * HH + c) = *(uint4*)res;
}

// ---------------- assignment head via MFMA ----------------
__global__ __launch_bounds__(256) void assign_mfma(const __half* __restrict__ Hb,
                                                   const __half* __restrict__ WaT,
                                                   const float* __restrict__ ba,
                                                   const float* __restrict__ degf,
                                                   float* __restrict__ out_assign,
                                                   __half* __restrict__ out_f16,
                                                   float* __restrict__ scal) {
    int t = threadIdx.x;
    int wave = t >> 6, lane = t & 63, quad = lane >> 4, l16 = lane & 15;
    int nb = blockIdx.x * 256 + wave * 64;

    f32x4 acc[4] = {};
    const __half* bp = WaT + l16 * HH + quad * 8;
    const __half* ap[4];
#pragma unroll
    for (int mi = 0; mi < 4; mi++) {
        int r = nb + mi * 16 + l16;
        if (r >= NN) r = NN - 1;
        ap[mi] = Hb + (size_t)r * HH + quad * 8;
    }
#pragma unroll
    for (int s = 0; s < 8; s++) {
        half8_t bf = *(const half8_t*)(bp + s * 32);
#pragma unroll
        for (int mi = 0; mi < 4; mi++) {
            half8_t af = *(const half8_t*)(ap[mi] + s * 32);
            acc[mi] = __builtin_amdgcn_mfma_f32_16x16x32_f16(af, bf, acc[mi], 0, 0, 0);
        }
    }

    float myb = ba[l16];
    float lcs = 0.f, ldS = 0.f, lent = 0.f;
#pragma unroll
    for (int mi = 0; mi < 4; mi++) {
#pragma unroll
        for (int r = 0; r < 4; r++) {
            int node = nb + mi * 16 + quad * 4 + r;
            bool ok = node < NN;
            float logit = acc[mi][r] + myb;
            float mx = logit;
            for (int o = 1; o < 16; o <<= 1) mx = fmaxf(mx, __shfl_xor(mx, o, 16));
            float e = expf(logit - mx);
            float sum = e;
            for (int o = 1; o < 16; o <<= 1) sum += __shfl_xor(sum, o, 16);
            float a = e / sum;
            if (ok) {
                out_assign[(size_t)node * KK + l16] = a;
                out_f16[(size_t)node * KK + l16] = __float2half(a);
                lcs += a;
                ldS += degf[node] * a;
                lent += a * logf(a + 1e-8f);
            }
        }
    }
    lcs += __shfl_xor(lcs, 16); lcs += __shfl_xor(lcs, 32);
    ldS += __shfl_xor(ldS, 16); ldS += __shfl_xor(ldS, 32);
    for (int o = 32; o >= 1; o >>= 1) lent += __shfl_xor(lent, o);
    if (quad == 0) {
        atomicAdd(&scal[l16], lcs);
        atomicAdd(&scal[16 + l16], ldS);
    }
    if (lane == 0) atomicAdd(&scal[33], lent);
}

// ---------------- fused trace(S^T A S): 4 edges per thread, f16 assignments ----------------
__device__ inline float dot16h(const __half* a, const __half* b) {
    uint4 a0 = *(const uint4*)a, a1 = *(const uint4*)(a + 8);
    uint4 b0 = *(const uint4*)b, b1 = *(const uint4*)(b + 8);
    float p = 0.f;
    const __half2* xa = (const __half2*)&a0;
    const __half2* xb = (const __half2*)&b0;
#pragma unroll
    for (int i = 0; i < 4; i++) {
        float2 u = __half22float2(xa[i]), v = __half22float2(xb[i]);
        p += u.x * v.x + u.y * v.y;
    }
    xa = (const __half2*)&a1; xb = (const __half2*)&b1;
#pragma unroll
    for (int i = 0; i < 4; i++) {
        float2 u = __half22float2(xa[i]), v = __half22float2(xb[i]);
        p += u.x * v.x + u.y * v.y;
    }
    return p;
}

__global__ __launch_bounds__(256) void edge_trace(const int4* __restrict__ src4,
                                                  const int4* __restrict__ dst4,
                                                  const __half* __restrict__ Ah,
                                                  float* __restrict__ scal) {
    int e = blockIdx.x * blockDim.x + threadIdx.x;
    float p = 0.f;
    if (e < EE / 4) {
        int4 s = src4[e], d = dst4[e];
        p += dot16h(Ah + (size_t)s.x * KK, Ah + (size_t)d.x * KK);
        p += dot16h(Ah + (size_t)s.y * KK, Ah + (size_t)d.y * KK);
        p += dot16h(Ah + (size_t)s.z * KK, Ah + (size_t)d.z * KK);
        p += dot16h(Ah + (size_t)s.w * KK, Ah + (size_t)d.w * KK);
    }
    for (int o = 32; o >= 1; o >>= 1) p += __shfl_xor(p, o);
    __shared__ float sp;
    if (threadIdx.x == 0) sp = 0.f;
    __syncthreads();
    if ((threadIdx.x & 63) == 0) atomicAdd(&sp, p);
    __syncthreads();
    if (threadIdx.x == 0) atomicAdd(&scal[32], sp);
}

// ---------------- pooled partial: pool_acc[k][d] += sum_n a[n][k]*emb[n][d] ----------------
#define PCH 125
__global__ __launch_bounds__(256) void pooled_partial(const float* __restrict__ emb,
                                                      const float* __restrict__ assign,
                                                      float* __restrict__ pool_acc) {
    int d = blockIdx.x * 256 + threadIdx.x;
    int c0 = blockIdx.y * PCH;
    float acc[KK];
#pragma unroll
    for (int k = 0; k < KK; k++) acc[k] = 0.f;
    __shared__ float sa[PCH * KK];  // 8 KB
    {
        const float4* srcv = (const float4*)(assign + (size_t)c0 * KK);
        float4* dstv = (float4*)sa;
        for (int i = threadIdx.x; i < PCH * KK / 4; i += 256) dstv[i] = srcv[i];
    }
    __syncthreads();
    for (int j = 0; j < PCH; j++) {
        float ev = emb[(size_t)(c0 + j) * DD + d];
#pragma unroll
        for (int k4 = 0; k4 < 4; k4++) {
            float4 s4 = *(const float4*)&sa[j * KK + k4 * 4];
            acc[k4 * 4 + 0] += s4.x * ev;
            acc[k4 * 4 + 1] += s4.y * ev;
            acc[k4 * 4 + 2] += s4.z * ev;
            acc[k4 * 4 + 3] += s4.w * ev;
        }
    }
#pragma unroll
    for (int k = 0; k < KK; k++) atomicAdd(&pool_acc[k * DD + d], acc[k]);
}

// ---------------- finalize: pooled normalize + scalar losses ----------------
__global__ void finalize(const float* __restrict__ pool_acc, const float* __restrict__ scal,
                         float* __restrict__ out) {
    int bx = blockIdx.x, t = threadIdx.x;
    if (bx < 32) {
        int i = bx * 256 + t;  // 0..8191
        int k = i / DD;
        out[800000 + i] = pool_acc[i] / (scal[k] + 1e-8f);
    } else if (t == 0) {
        float cs2 = 0.f, ds2 = 0.f;
        for (int k = 0; k < KK; k++) {
            cs2 += scal[k] * scal[k];
            ds2 += scal[16 + k] * scal[16 + k];
        }
        float two_m = (float)EE;  // sum(degrees) == E, 2m == E
        float normalizer = ds2 / two_m;
        float trace = scal[32];
        float spectral = -(trace - (float)KK * normalizer) / two_m;
        float collapse = sqrtf(cs2) / (float)NN * 4.0f - 1.0f;  // sqrt(K)=4
        float entl = 0.1f * scal[33] / (float)NN;
        out[808192] = spectral;
        out[808193] = collapse;  // COLLAPSE_REG = 1.0
        out[808194] = spectral + collapse + entl;
        out[808195] = entl;
    }
}

extern "C" void kernel_launch(void* const* d_in, const int* in_sizes, int n_in,
                              void* d_out, int out_size, void* d_ws, size_t ws_size,
                              hipStream_t stream) {
    const float* emb = (const float*)d_in[0];
    const int* esrc  = (const int*)d_in[1];
    const int* edst  = (const int*)d_in[2];
    const float* W1  = (const float*)d_in[3];
    const float* b1  = (const float*)d_in[4];
    const float* W2  = (const float*)d_in[5];
    const float* b2  = (const float*)d_in[6];
    const float* Wa  = (const float*)d_in[7];
    const float* ba  = (const float*)d_in[8];
    float* out = (float*)d_out;

    // workspace layout (4B units unless noted) — total ~58 MB
    int* indeg      = (int*)d_ws;            // 50000
    int* outdeg     = indeg + 50000;         // 50000
    int* cur        = outdeg + 50000;        // 50000
    float* pool_acc = (float*)(cur + 50000); // 8192
    float* scal     = pool_acc + 8192;       // 64
    int* part       = (int*)(scal + 64);     // 256 (scan partials)
    int* off        = part + 256;            // 50001 (+pad to 50004)
    int* nbr        = off + 50004;           // 800000
    float* dis      = (float*)(nbr + 800000);// 50000
    float* degf     = dis + 50000;           // 50000
    __half* wgt     = (__half*)(degf + 50000);   // 800000 f16 (1.6 MB)
    __half* Wt1     = wgt + 800000;              // 256*512 f16
    __half* Wt2     = Wt1 + 256 * 512;           // 256*256 f16
    __half* WaT     = Wt2 + 256 * 256;           // 16*256 f16
    __half* T       = WaT + 16 * 256;            // row-major [NN][256] f16 (25.6 MB)
    __half* Hb      = T + (size_t)NN * HH;       // row-major [NN][256] f16 (25.6 MB)
    __half* Ah      = T;  // f16 assignments alias T (dead after agg2)

    // zero the atomically-accumulated region: indeg/outdeg/cur/pool_acc/scal
    zero_kernel<<<dim3(619), 256, 0, stream>>>((int*)d_ws, 158256);
    count_kernel<<<dim3(782), 256, 0, stream>>>((const int4*)esrc, (const int4*)edst,
                                                indeg, outdeg);

    // CSR offsets: 3-phase scan (+ dis/degf in p1)
    scan_p1<<<dim3(NB_SCAN), 256, 0, stream>>>(indeg, part, NN, outdeg, dis, degf);
    scan_p2<<<dim3(1), 256, 0, stream>>>(part, NB_SCAN, off + NN);
    scan_p3<<<dim3(NB_SCAN), 256, 0, stream>>>(indeg, part, off, NN);
    scatter_kernel<<<dim3(782), 256, 0, stream>>>((const int4*)esrc, (const int4*)edst,
                                                  off, cur, dis, nbr, wgt);

    // weights -> f16 transposed (fused: W1, W2, Wa)
    transpose_w<<<dim3(784), 256, 0, stream>>>(W1, Wt1, W2, Wt2, Wa, WaT);

    // conv1: T = emb @ W1 ; Hb = selu(Ahat*T + b1)
    mfma_gemm<float, DD><<<dim3(392, 2), 256, 0, stream>>>(emb, Wt1, T, NN);
    agg_selu<<<dim3(6250), 256, 0, stream>>>(T, dis, off, nbr, wgt, b1, nullptr, Hb);

    // conv2: T = Hb @ W2 ; Hb = selu(Ahat*T + b2) + Hb (skip, in place)
    mfma_gemm<__half, HH><<<dim3(392, 2), 256, 0, stream>>>(Hb, Wt2, T, NN);
    agg_selu<<<dim3(6250), 256, 0, stream>>>(T, dis, off, nbr, wgt, b2, Hb, Hb);

    // head: assignments -> d_out[0..800000) (+f16 copy), loss partials
    assign_mfma<<<dim3(196), 256, 0, stream>>>(Hb, WaT, ba, degf, out, Ah, scal);
    edge_trace<<<dim3(782), 256, 0, stream>>>((const int4*)esrc, (const int4*)edst, Ah, scal);
    pooled_partial<<<dim3(2, 400), 256, 0, stream>>>(emb, out, pool_acc);
    finalize<<<dim3(33), 256, 0, stream>>>(pool_acc, scal, out);
}